// Round 13
// baseline (526.037 us; speedup 1.0000x reference)
//
#include <hip/hip_runtime.h>

#define BB 8
#define LQ 4096
#define LK 32768
#define DD 64
#define UU 8000
#define NU 45
#define TQ2 128
#define TUC 160
#define NCH (UU/TUC)   // 50 chunks
#define CHB (TUC*DD*2) // 20480 bytes per chunk per array
#define KT5 512
#define NT5 64

typedef short short8 __attribute__((ext_vector_type(8)));
typedef float floatx16 __attribute__((ext_vector_type(16)));

__device__ __forceinline__ float bf2f(unsigned short h){ return __uint_as_float(((unsigned int)h) << 16); }
__device__ __forceinline__ unsigned short f2bf(float f){
  unsigned int u = __float_as_uint(f);
  u += 0x7FFFu + ((u >> 16) & 1u);
  return (unsigned short)(u >> 16);
}
__device__ __forceinline__ unsigned int fkey(float v){
  unsigned int u = __float_as_uint(v);
  return (u & 0x80000000u) ? ~u : (u | 0x80000000u);
}

// ---------------- prep: gather K_samp rows, Dekker-split f32 -> bf16 hi+mid ---------------------
__global__ __launch_bounds__(256) void k_gather(const float* __restrict__ Kg, const int* __restrict__ idx,
                                                unsigned short* __restrict__ khi, unsigned short* __restrict__ kmid){
  const int b = blockIdx.y;
  const int row = blockIdx.x*32 + (threadIdx.x >> 3);
  const int oct = threadIdx.x & 7;
  const float* src = Kg + ((size_t)(b*LK + idx[row]))*DD + oct*8;
  float x[8];
  #pragma unroll
  for (int j=0;j<8;j++) x[j] = src[j];
  unsigned short h[8], m[8];
  #pragma unroll
  for (int j=0;j<8;j++){
    h[j] = f2bf(x[j]);
    m[j] = f2bf(x[j] - bf2f(h[j]));
  }
  const int osl = oct ^ (row & 7);                 // pre-swizzle the slot within the 8-row block
  size_t o = ((size_t)(b*UU + row))*DD + osl*8;
  #pragma unroll
  for (int j=0;j<8;j++){ khi[o+j]=h[j]; kmid[o+j]=m[j]; }
}

// partial sums of K_samp (for the exact mean term)
__global__ __launch_bounds__(64) void k_spart(const float* __restrict__ Kg, const int* __restrict__ idx,
                                              float* __restrict__ Spart){
  const int g = blockIdx.x, b = blockIdx.y, d = threadIdx.x;
  float acc = 0.0f;
  for (int j=0;j<64;j++){
    int u = g*64 + j;
    acc += Kg[((size_t)(b*LK + idx[u]))*DD + d];
  }
  Spart[((size_t)(b*125 + g))*DD + d] = acc;
}
__global__ __launch_bounds__(64) void k_sred(const float* __restrict__ Spart, float* __restrict__ Sb){
  const int b = blockIdx.x, d = threadIdx.x;
  float acc = 0.0f;
  for (int g=0; g<125; g++) acc += Spart[((size_t)(b*125 + g))*DD + d];
  Sb[b*DD + d] = acc;
}

// stage one 160-row chunk (khi+kmid, 40960 B) into LDS via global_load_lds.
__device__ __forceinline__ void stage_chunk(const char* gh, const char* gm,
                                            unsigned short* Bhb, unsigned short* Bmb,
                                            int w, int lane){
  #pragma unroll
  for (int i=0;i<5;i++){
    const int u = w*5 + i;   // 0..39, wave-uniform
    if (u < 20){
      __builtin_amdgcn_global_load_lds(
        (const __attribute__((address_space(1))) void*)(gh + u*1024 + lane*16),
        (__attribute__((address_space(3))) void*)((char*)Bhb + u*1024 + lane*16),
        16, 0, 0);
    } else {
      __builtin_amdgcn_global_load_lds(
        (const __attribute__((address_space(1))) void*)(gm + (u-20)*1024 + lane*16),
        (__attribute__((address_space(3))) void*)((char*)Bmb + (u-20)*1024 + lane*16),
        16, 0, 0);
    }
  }
}

// ---------------- Stage 1 (MFMA): approx max + arg-chunk per q ----------------------------------
// v7: chunk-parity split across 2 blocks (grid 512, each does 25 chunks) + LDS shrunk to exactly
// 81920 B (comb arrays aliased into dead Bh[0] after the loop) -> 2 independent blocks/CU whose
// barrier drains overlap. Per-parity (max,argchunk) combined in k_bucket with sequential tie-break.
__global__ __launch_bounds__(512,2) void k_Mm(const float* __restrict__ q,
                                              const unsigned short* __restrict__ khi,
                                              const unsigned short* __restrict__ kmid,
                                              float* __restrict__ amax2, int* __restrict__ acarg2){
  const int wg = blockIdx.x;
  const int b = wg & 7, par = (wg >> 3) & 1, qt = wg >> 4;
  const int tid = threadIdx.x;
  const int w = tid >> 6, lane = tid & 63;
  const int tr = w & 3, sp = w >> 2;
  const int l31 = lane & 31, lh = lane >> 5;
  __shared__ __align__(16) unsigned short Bh[2][TUC*DD];   // 40960 B
  __shared__ __align__(16) unsigned short Bm[2][TUC*DD];   // 40960 B  -> total exactly 81920 B

  const int qrow = qt*TQ2 + tr*32 + l31;
  short8 ahi[4], amid[4];
  {
    const float* qp = q + ((size_t)(b*LQ) + qrow)*DD;
    #pragma unroll
    for (int s=0;s<4;s++){
      const int d0 = s*16 + lh*8;
      float4 x0 = *(const float4*)(qp + d0);
      float4 x1 = *(const float4*)(qp + d0 + 4);
      float xs[8] = {x0.x,x0.y,x0.z,x0.w,x1.x,x1.y,x1.z,x1.w};
      short8 h, m;
      #pragma unroll
      for (int j=0;j<8;j++){
        unsigned short hb = f2bf(xs[j]);
        unsigned short mb = f2bf(xs[j] - bf2f(hb));
        h[j] = (short)hb; m[j] = (short)mb;
      }
      ahi[s]=h; amid[s]=m;
    }
  }

  float vmax[16]; int carg[16];
  #pragma unroll
  for (int r=0;r<16;r++){ vmax[r]=-INFINITY; carg[r]=0; }

  const size_t kbyte = (size_t)b*UU*DD*2;
  const char* ghbase = (const char*)khi + kbyte;
  const char* gmbase = (const char*)kmid + kbyte;

  // prologue: issue chunk `par` into buffer 0
  stage_chunk(ghbase + (size_t)par*CHB, gmbase + (size_t)par*CHB, &Bh[0][0], &Bm[0][0], w, lane);
  int cur = 0;
  int it = 0;

  for (int c = par; c < NCH; c += 2, it++){
    __syncthreads();   // implicit vmcnt(0) drain: buf[cur] ready; all waves done with buf[cur^1]
    if (c+2 < NCH){
      stage_chunk(ghbase + (size_t)(c+2)*CHB, gmbase + (size_t)(c+2)*CHB,
                  &Bh[cur^1][0], &Bm[cur^1][0], w, lane);
    }
    float lmax[16];
    #pragma unroll
    for (int r=0;r<16;r++) lmax[r] = -INFINITY;
    // iteration-parity-alternating split of the 5 tiles between sp waves (3/2 balanced long-run)
    for (int t = ((it ^ sp) & 1); t < 5; t += 2){
      floatx16 accA = {0.f,0.f,0.f,0.f,0.f,0.f,0.f,0.f,0.f,0.f,0.f,0.f,0.f,0.f,0.f,0.f};
      floatx16 accB = {0.f,0.f,0.f,0.f,0.f,0.f,0.f,0.f,0.f,0.f,0.f,0.f,0.f,0.f,0.f,0.f};
      #pragma unroll
      for (int s=0;s<4;s++){
        const int eo = (t*32 + l31)*DD + (((s*2 + lh) ^ (l31 & 7))*8);
        short8 bh = *(const short8*)(&Bh[cur][eo]);
        short8 bm = *(const short8*)(&Bm[cur][eo]);
        if (s & 1){
          accB = __builtin_amdgcn_mfma_f32_32x32x16_bf16(amid[s], bh, accB, 0, 0, 0);
          accB = __builtin_amdgcn_mfma_f32_32x32x16_bf16(ahi[s],  bm, accB, 0, 0, 0);
          accB = __builtin_amdgcn_mfma_f32_32x32x16_bf16(ahi[s],  bh, accB, 0, 0, 0);
        } else {
          accA = __builtin_amdgcn_mfma_f32_32x32x16_bf16(amid[s], bh, accA, 0, 0, 0);
          accA = __builtin_amdgcn_mfma_f32_32x32x16_bf16(ahi[s],  bm, accA, 0, 0, 0);
          accA = __builtin_amdgcn_mfma_f32_32x32x16_bf16(ahi[s],  bh, accA, 0, 0, 0);
        }
      }
      #pragma unroll
      for (int r=0;r<16;r++) lmax[r] = fmaxf(lmax[r], accA[r] + accB[r]);
    }
    #pragma unroll
    for (int r=0;r<16;r++){
      if (lmax[r] > vmax[r]){ vmax[r] = lmax[r]; carg[r] = c; }
    }
    cur ^= 1;
  }
  #pragma unroll
  for (int st=1; st<32; st<<=1){
    #pragma unroll
    for (int r=0;r<16;r++){
      float ov = __shfl_xor(vmax[r], st);
      int   oc = __shfl_xor(carg[r], st);
      if (ov > vmax[r]){ vmax[r]=ov; carg[r]=oc; }
    }
  }
  // comb arrays aliased into Bh[0] (staging finished; all compute done after this barrier)
  __syncthreads();
  float* combV = (float*)&Bh[0][0];            // [TQ2][2]
  int*   combC = (int*)(combV + TQ2*2);        // [TQ2][2]
  if (l31 == 0){
    #pragma unroll
    for (int r=0;r<16;r++){
      int m = (r&3) + 8*(r>>2) + 4*lh;
      int ql = tr*32 + m;
      combV[ql*2 + sp] = vmax[r];
      combC[ql*2 + sp] = carg[r];
    }
  }
  __syncthreads();
  if (tid < TQ2){
    float v0 = combV[tid*2+0], v1 = combV[tid*2+1];
    int   c0 = combC[tid*2+0], c1 = combC[tid*2+1];
    bool t1 = v1 > v0;
    size_t o = ((size_t)(par*BB + b))*LQ + qt*TQ2 + tid;
    amax2[o]  = t1 ? v1 : v0;
    acarg2[o] = t1 ? c1 : c0;
  }
}

// ---------------- bucket q rows by their argmax chunk (combines the 2 parity halves) ------------
__global__ __launch_bounds__(256) void k_bucket(const float* __restrict__ amax2,
                                                const int* __restrict__ acarg2,
                                                int* __restrict__ qlist, int* __restrict__ bstart){
  const int b = blockIdx.x, tid = threadIdx.x;
  __shared__ unsigned char chs[LQ];   // combined chunk per q (<50 fits a byte)
  __shared__ int cnt[NCH];
  __shared__ int pos[NCH];
  if (tid < NCH) cnt[tid] = 0;
  __syncthreads();
  for (int qq = tid; qq < LQ; qq += 256){
    float v0 = amax2[((size_t)b)*LQ + qq];
    float v1 = amax2[((size_t)(BB + b))*LQ + qq];
    int   c0 = acarg2[((size_t)b)*LQ + qq];
    int   c1 = acarg2[((size_t)(BB + b))*LQ + qq];
    // sequential first-win semantics: larger value wins; on exact tie, lower chunk index
    int ch = (v1 > v0 || (v1 == v0 && c1 < c0)) ? c1 : c0;
    ch = (ch < 0) ? 0 : ((ch >= NCH) ? NCH-1 : ch);
    chs[qq] = (unsigned char)ch;
    atomicAdd(&cnt[ch], 1);
  }
  __syncthreads();
  if (tid == 0){
    int acc = 0;
    for (int c=0;c<NCH;c++){ pos[c] = acc; bstart[b*64 + c] = acc; acc += cnt[c]; }
    bstart[b*64 + NCH] = acc;   // == LQ
  }
  __syncthreads();
  for (int qq = tid; qq < LQ; qq += 256){
    int ch = chs[qq];
    int p = atomicAdd(&pos[ch], 1);
    p = (p < 0) ? 0 : ((p >= LQ) ? LQ-1 : p);
    qlist[(size_t)b*LQ + p] = qq;
  }
}

// ---------------- refinement: 4 blocks per (chunk,b) + XCD affinity -----------------------------
__global__ __launch_bounds__(256,3) void k_refb(const float* __restrict__ q, const float* __restrict__ Kg,
                                                const int* __restrict__ idx, const float* __restrict__ Sb,
                                                const int* __restrict__ qlist, const int* __restrict__ bstart,
                                                float* __restrict__ M){
  const int wg = blockIdx.x;
  const int b = wg & 7;
  const int r0 = wg >> 3;
  const int ch = r0 >> 2, part = r0 & 3;
  const int tid = threadIdx.x;
  const int w = tid >> 6, lane = tid & 63;
  const int quad = lane & 3, rg = lane >> 2;
  __shared__ __align__(16) float Kl[TUC*DD];   // 40 KB
  float4* Kl4 = (float4*)Kl;
  for (int g = tid; g < TUC*16; g += 256){
    int row = g >> 4, s = g & 15;
    int gidx = idx[ch*TUC + row];
    float4 v = *(const float4*)(Kg + ((size_t)(b*LK + gidx))*DD + s*4);
    Kl4[row*16 + (s ^ (row & 7))] = v;
  }
  __syncthreads();

  const float4* sp4 = (const float4*)(Sb + b*DD + quad*16);
  const float4 S0 = sp4[0], S1 = sp4[1], S2 = sp4[2], S3 = sp4[3];
  const int sl0 = ((quad<<2)|0) ^ (rg & 7);
  const int sl1 = ((quad<<2)|1) ^ (rg & 7);
  const int sl2 = ((quad<<2)|2) ^ (rg & 7);
  const int sl3 = ((quad<<2)|3) ^ (rg & 7);
  const int rbs = rg*16;
  const int s0 = bstart[b*64 + ch], s1 = bstart[b*64 + ch + 1];
  const int gw = part*4 + w;                       // 0..15 across the four blocks of this bucket

  for (int i = s0 + (gw<<1); i < s1; i += 32){
    const int qa = qlist[(size_t)b*LQ + i];
    const int i2 = (i+1 < s1) ? i+1 : i;
    const int qb = qlist[(size_t)b*LQ + i2];
    const float4* ap = (const float4*)(q + ((size_t)(b*LQ + qa))*DD + quad*16);
    const float4* bp = (const float4*)(q + ((size_t)(b*LQ + qb))*DD + quad*16);
    const float4 A0 = ap[0], A1 = ap[1], A2 = ap[2], A3 = ap[3];
    const float4 B0 = bp[0], B1 = bp[1], B2 = bp[2], B3 = bp[3];
    float mxa = -INFINITY, mxb = -INFINITY;
    #pragma unroll
    for (int p=0;p<10;p++){
      const int base = p*256 + rbs;
      float4 k0 = Kl4[base + sl0];
      float4 k1 = Kl4[base + sl1];
      float4 k2 = Kl4[base + sl2];
      float4 k3 = Kl4[base + sl3];
      float a0 = A0.x*k0.x, a1 = A0.y*k0.y, a2 = A0.z*k0.z, a3 = A0.w*k0.w;
      a0 = fmaf(A1.x,k1.x,a0); a1 = fmaf(A1.y,k1.y,a1); a2 = fmaf(A1.z,k1.z,a2); a3 = fmaf(A1.w,k1.w,a3);
      a0 = fmaf(A2.x,k2.x,a0); a1 = fmaf(A2.y,k2.y,a1); a2 = fmaf(A2.z,k2.z,a2); a3 = fmaf(A2.w,k2.w,a3);
      a0 = fmaf(A3.x,k3.x,a0); a1 = fmaf(A3.y,k3.y,a1); a2 = fmaf(A3.z,k3.z,a2); a3 = fmaf(A3.w,k3.w,a3);
      float c0 = B0.x*k0.x, c1 = B0.y*k0.y, c2 = B0.z*k0.z, c3 = B0.w*k0.w;
      c0 = fmaf(B1.x,k1.x,c0); c1 = fmaf(B1.y,k1.y,c1); c2 = fmaf(B1.z,k1.z,c2); c3 = fmaf(B1.w,k1.w,c3);
      c0 = fmaf(B2.x,k2.x,c0); c1 = fmaf(B2.y,k2.y,c1); c2 = fmaf(B2.z,k2.z,c2); c3 = fmaf(B2.w,k2.w,c3);
      c0 = fmaf(B3.x,k3.x,c0); c1 = fmaf(B3.y,k3.y,c1); c2 = fmaf(B3.z,k3.z,c2); c3 = fmaf(B3.w,k3.w,c3);
      float sa = (a0+a1)+(a2+a3);
      float sc = (c0+c1)+(c2+c3);
      sa += __shfl_xor(sa, 1);
      sa += __shfl_xor(sa, 2);
      sc += __shfl_xor(sc, 1);
      sc += __shfl_xor(sc, 2);
      mxa = fmaxf(mxa, sa);
      mxb = fmaxf(mxb, sc);
    }
    #pragma unroll
    for (int st=4; st<64; st<<=1){
      mxa = fmaxf(mxa, __shfl_xor(mxa, st));
      mxb = fmaxf(mxb, __shfl_xor(mxb, st));
    }
    // exact mean terms
    float m0 = A0.x*S0.x, m1 = A0.y*S0.y, m2 = A0.z*S0.z, m3 = A0.w*S0.w;
    m0 = fmaf(A1.x,S1.x,m0); m1 = fmaf(A1.y,S1.y,m1); m2 = fmaf(A1.z,S1.z,m2); m3 = fmaf(A1.w,S1.w,m3);
    m0 = fmaf(A2.x,S2.x,m0); m1 = fmaf(A2.y,S2.y,m1); m2 = fmaf(A2.z,S2.z,m2); m3 = fmaf(A2.w,S2.w,m3);
    m0 = fmaf(A3.x,S3.x,m0); m1 = fmaf(A3.y,S3.y,m1); m2 = fmaf(A3.z,S3.z,m2); m3 = fmaf(A3.w,S3.w,m3);
    float msa = (m0+m1)+(m2+m3);
    msa += __shfl_xor(msa, 1);
    msa += __shfl_xor(msa, 2);
    float n0 = B0.x*S0.x, n1 = B0.y*S0.y, n2 = B0.z*S0.z, n3 = B0.w*S0.w;
    n0 = fmaf(B1.x,S1.x,n0); n1 = fmaf(B1.y,S1.y,n1); n2 = fmaf(B1.z,S1.z,n2); n3 = fmaf(B1.w,S1.w,n3);
    n0 = fmaf(B2.x,S2.x,n0); n1 = fmaf(B2.y,S2.y,n1); n2 = fmaf(B2.z,S2.z,n2); n3 = fmaf(B2.w,S2.w,n3);
    n0 = fmaf(B3.x,S3.x,n0); n1 = fmaf(B3.y,S3.y,n1); n2 = fmaf(B3.z,S3.z,n2); n3 = fmaf(B3.w,S3.w,n3);
    float msb = (n0+n1)+(n2+n3);
    msb += __shfl_xor(msb, 1);
    msb += __shfl_xor(msb, 2);
    if (lane == 0){
      M[(size_t)b*LQ + qa] = mxa - msa * (1.0f/8000.0f);
      if (i2 != i) M[(size_t)b*LQ + qb] = mxb - msb * (1.0f/8000.0f);
    }
  }
}

// ---------------- Stage 2: per-batch stable bottom-45 of M (cached local-min argmin) ------------
__global__ __launch_bounds__(256) void k_select(const float* __restrict__ Mg,
                                                const float* __restrict__ q,
                                                int* __restrict__ MtopG, float* __restrict__ Qred){
  const int b = blockIdx.x, tid = threadIdx.x;
  __shared__ float Mv[LQ];
  __shared__ unsigned long long wmin[4];
  __shared__ int mtop[NU];
  __shared__ int selB;
  for (int qq = tid; qq < LQ; qq += 256) Mv[qq] = Mg[(size_t)b*LQ + qq];
  __syncthreads();
  unsigned long long lm = ~0ull;
  #pragma unroll
  for (int i=0;i<16;i++){
    int qq = tid + 256*i;
    unsigned long long kk = (((unsigned long long)fkey(Mv[qq]))<<32) | (unsigned int)qq;
    lm = (kk < lm) ? kk : lm;
  }
  for (int i=0;i<NU;i++){
    unsigned long long v = lm;
    #pragma unroll
    for (int st=1; st<64; st<<=1){
      unsigned long long o = __shfl_xor(v, st);
      v = (o < v) ? o : v;
    }
    if ((tid & 63) == 0) wmin[tid>>6] = v;
    __syncthreads();
    if (tid == 0){
      unsigned long long g01 = (wmin[0] < wmin[1]) ? wmin[0] : wmin[1];
      unsigned long long g23 = (wmin[2] < wmin[3]) ? wmin[2] : wmin[3];
      unsigned long long g = (g01 < g23) ? g01 : g23;
      int sel = (int)(g & 0xFFFFFFFFull);
      mtop[i] = sel; selB = sel; Mv[sel] = INFINITY;
    }
    __syncthreads();
    int sel = selB;
    if (tid == (sel & 255)){
      unsigned long long nl = ~0ull;
      #pragma unroll
      for (int j=0;j<16;j++){
        int qq = tid + 256*j;
        unsigned long long kk = (((unsigned long long)fkey(Mv[qq]))<<32) | (unsigned int)qq;
        nl = (kk < nl) ? kk : nl;
      }
      lm = nl;
    }
    __syncthreads();
  }
  if (tid < NU) MtopG[b*NU + tid] = mtop[tid];
  for (int e = tid; e < NU*DD; e += 256){
    int ui = e >> 6, d = e & 63;
    Qred[((size_t)(b*NU + ui))*DD + d] = q[((size_t)(b*LQ + mtop[ui]))*DD + d];
  }
}

// ---------------- Stage 3: attn_scores + per-wave softmax partials ------------------------------
#define QFMA(i) { float4 p = qr4[i]; \
  a0 = fmaf(kv##i.x, p.x, a0); a1 = fmaf(kv##i.y, p.y, a1); \
  a2 = fmaf(kv##i.z, p.z, a2); a3 = fmaf(kv##i.w, p.w, a3); }

__global__ __launch_bounds__(256) void k_scores(const float* __restrict__ Kg,
                                                const float* __restrict__ Qred,
                                                float* __restrict__ out1,
                                                float* __restrict__ pm, float* __restrict__ pl){
  const int b = blockIdx.y;
  const int k = blockIdx.x*256 + threadIdx.x;
  const int lane = threadIdx.x & 63, w = threadIdx.x >> 6;
  const int pi = blockIdx.x*4 + w;                 // 0..511 partial slot
  const float4* kp4 = (const float4*)(Kg + ((size_t)(b*LK + k))*DD);
  const float4 kv0  = kp4[0],  kv1  = kp4[1],  kv2  = kp4[2],  kv3  = kp4[3];
  const float4 kv4  = kp4[4],  kv5  = kp4[5],  kv6  = kp4[6],  kv7  = kp4[7];
  const float4 kv8  = kp4[8],  kv9  = kp4[9],  kv10 = kp4[10], kv11 = kp4[11];
  const float4 kv12 = kp4[12], kv13 = kp4[13], kv14 = kp4[14], kv15 = kp4[15];
  for (int u=0; u<NU; u++){
    const float4* qr4 = (const float4*)(Qred + ((size_t)(b*NU+u))*DD);
    float a0 = 0.f, a1 = 0.f, a2 = 0.f, a3 = 0.f;
    QFMA(0)  QFMA(1)  QFMA(2)  QFMA(3)
    QFMA(4)  QFMA(5)  QFMA(6)  QFMA(7)
    QFMA(8)  QFMA(9)  QFMA(10) QFMA(11)
    QFMA(12) QFMA(13) QFMA(14) QFMA(15)
    float s = ((a0+a1)+(a2+a3)) * 0.125f;
    out1[((size_t)(b*NU+u)<<15) + k] = s;
    // wave-level softmax partials
    float mw = s;
    #pragma unroll
    for (int st=1; st<64; st<<=1) mw = fmaxf(mw, __shfl_xor(mw, st));
    float e = __expf(s - mw);
    #pragma unroll
    for (int st=1; st<64; st<<=1) e += __shfl_xor(e, st);
    if (lane == 0){
      size_t r = (size_t)(b*NU + u);
      pm[r*512 + pi] = mw;
      pl[r*512 + pi] = e;
    }
  }
}

// ---------------- Stage 4a: combine softmax partials (1.4 MB, replaces 94 MB pass) --------------
__global__ __launch_bounds__(256) void k_rowred(const float* __restrict__ pm, const float* __restrict__ pl,
                                                float* __restrict__ rowm, float* __restrict__ rowinvl){
  const int r = blockIdx.x, tid = threadIdx.x;
  __shared__ float red[256];
  float m = -INFINITY;
  for (int i = tid; i < 512; i += 256) m = fmaxf(m, pm[(size_t)r*512 + i]);
  red[tid] = m; __syncthreads();
  for (int s=128;s>0;s>>=1){ if (tid<s) red[tid] = fmaxf(red[tid], red[tid+s]); __syncthreads(); }
  m = red[0]; __syncthreads();
  float sm = 0.0f;
  for (int i = tid; i < 512; i += 256)
    sm += pl[(size_t)r*512 + i] * __expf(pm[(size_t)r*512 + i] - m);
  red[tid] = sm; __syncthreads();
  for (int s=128;s>0;s>>=1){ if (tid<s) red[tid] += red[tid+s]; __syncthreads(); }
  if (tid==0){ rowm[r] = m; rowinvl[r] = 1.0f/red[0]; }
}

// ---------------- Stage 4b: PV partials per k-tile ----------------------------------------------
__global__ __launch_bounds__(512) void k_pv(const float* __restrict__ Vg,
                                            const float* __restrict__ out1,
                                            const float* __restrict__ rowm, const float* __restrict__ rowinvl,
                                            float* __restrict__ pvpart){
  const int kt = blockIdx.x, b = blockIdx.y, tid = threadIdx.x;
  const int lane = tid & 63, w = tid >> 6;
  const int u0 = w*6;
  __shared__ float Vl[128][65];
  __shared__ __align__(16) float Pl[48][132];
  float acc[6];
  #pragma unroll
  for (int j=0;j<6;j++) acc[j] = 0.0f;
  for (int sc=0; sc<4; sc++){
    const int k0 = kt*KT5 + sc*128;
    {
      int r = tid >> 2, h = tid & 3;
      const float* vp = Vg + ((size_t)(b*LK + k0 + r))*DD + h*16;
      #pragma unroll
      for (int j=0;j<4;j++){
        float4 t = ((const float4*)vp)[j];
        Vl[r][h*16 + 4*j]   = t.x;
        Vl[r][h*16 + 4*j+1] = t.y;
        Vl[r][h*16 + 4*j+2] = t.z;
        Vl[r][h*16 + 4*j+3] = t.w;
      }
    }
    for (int e = tid; e < 48*128; e += 512){
      int u = e >> 7, kk = e & 127;
      float p = 0.0f;
      if (u < NU){
        int r = b*NU + u;
        float s = out1[((size_t)r<<15) + k0 + kk];
        p = __expf(s - rowm[r]) * rowinvl[r];
      }
      Pl[u][kk] = p;
    }
    __syncthreads();
    for (int kk4=0; kk4<32; kk4++){
      float v0 = Vl[4*kk4+0][lane];
      float v1 = Vl[4*kk4+1][lane];
      float v2 = Vl[4*kk4+2][lane];
      float v3 = Vl[4*kk4+3][lane];
      #pragma unroll
      for (int j=0;j<6;j++){
        float4 p = *reinterpret_cast<const float4*>(&Pl[u0+j][4*kk4]);
        acc[j] = fmaf(p.w, v3, fmaf(p.z, v2, fmaf(p.y, v1, fmaf(p.x, v0, acc[j]))));
      }
    }
    __syncthreads();
  }
  #pragma unroll
  for (int j=0;j<6;j++){
    if (u0 + j < NU){
      pvpart[(((size_t)(b*NU + u0 + j))*NT5 + kt)*DD + lane] = acc[j];
    }
  }
}

// ---------------- Stage 5: reduce PV partials -> output 0 ---------------------------------------
__global__ __launch_bounds__(256) void k_final(const float* __restrict__ pvpart, float* __restrict__ out0){
  int e = blockIdx.x*256 + threadIdx.x;
  if (e >= BB*NU*DD) return;
  int d = e & 63; int r = e >> 6;
  float s = 0.0f;
  for (int t=0;t<NT5;t++) s += pvpart[((size_t)r*NT5 + t)*DD + d];
  out0[e] = s;
}

extern "C" void kernel_launch(void* const* d_in, const int* in_sizes, int n_in,
                              void* d_out, int out_size, void* d_ws, size_t ws_size,
                              hipStream_t stream){
  const float* q  = (const float*)d_in[0];
  const float* K  = (const float*)d_in[1];
  const float* V  = (const float*)d_in[2];
  const int* idx  = (const int*)d_in[3];
  float* out0 = (float*)d_out;
  float* out1 = out0 + BB*NU*DD;

  float* ws = (float*)d_ws;
  unsigned short* khi  = (unsigned short*)ws;                        // 8*8000*64 bf16 = 8.192 MB
  float*  pvpart = ws;                                               // 5.90 MB (aliases khi; khi dead by k_pv)
  unsigned short* kmid = (unsigned short*)(ws + (size_t)BB*UU*DD/2); // 8.192 MB
  float* pm      = ws + (size_t)BB*UU*DD/2;                          // 360*512 f32 (aliases kmid; kmid dead after k_Mm)
  float* pl      = pm + (size_t)BB*NU*512;                           // 360*512 f32
  float* Spart   = ws + (size_t)BB*UU*DD;                            // 8*125*64 = 64000
  float* Sb      = Spart + 64000;                                    // 512
  float* amax2   = Sb + 512;                                         // 2*8*4096 = 65536
  int*   acarg2  = (int*)(amax2 + 2*(size_t)BB*LQ);                  // 65536
  float* Mbq     = (float*)(acarg2 + 2*(size_t)BB*LQ);               // 32768
  float* Qred    = Mbq + BB*LQ;                                      // 23040
  float* rowm    = Qred + (size_t)BB*NU*DD;                          // 512
  float* rowinvl = rowm + 512;                                       // 512
  int*   Mtop    = (int*)(rowinvl + 512);                            // 360 (pad 512)
  int*   qlist   = Mtop + 512;                                       // 32768
  int*   bstart  = qlist + (size_t)BB*LQ;                            // 512

  k_gather<<<dim3(UU/32, BB), 256, 0, stream>>>(K, idx, khi, kmid);
  k_spart<<<dim3(125, BB), 64, 0, stream>>>(K, idx, Spart);
  k_sred<<<BB, 64, 0, stream>>>(Spart, Sb);
  k_Mm<<<(LQ/TQ2)*2*BB, 512, 0, stream>>>(q, khi, kmid, amax2, acarg2);
  k_bucket<<<BB, 256, 0, stream>>>(amax2, acarg2, qlist, bstart);
  k_refb<<<NCH*4*BB, 256, 0, stream>>>(q, K, idx, Sb, qlist, bstart, Mbq);
  k_select<<<BB, 256, 0, stream>>>(Mbq, q, Mtop, Qred);
  k_scores<<<dim3(LK/256, BB), 256, 0, stream>>>(K, Qred, out1, pm, pl);
  k_rowred<<<BB*NU, 256, 0, stream>>>(pm, pl, rowm, rowinvl);
  k_pv<<<dim3(NT5, BB), 512, 0, stream>>>(V, out1, rowm, rowinvl, pvpart);
  k_final<<<(BB*NU*DD + 255)/256, 256, 0, stream>>>(pvpart, out0);
}